// Round 21
// 674.408 us; speedup vs baseline: 1.6996x; 1.0050x over previous
//
#include <hip/hip_runtime.h>
#include <math.h>

#define DEV __device__ __forceinline__

DEV float sigmoid_(float x){ return 1.f/(1.f+__expf(-x)); }
DEV float silu_(float x){ return x * sigmoid_(x); }
DEV float softplus_(float x){ return (x > 20.f) ? x : log1pf(__expf(x)); }
DEV float gelu_(float x){ return 0.5f*x*(1.f + erff(x*0.70710678118654752440f)); }

typedef __attribute__((ext_vector_type(8))) short short8v;
typedef __attribute__((ext_vector_type(4))) short short4v;
typedef __attribute__((ext_vector_type(4))) float floatx4;

DEV float bfu_(unsigned short u){ return __uint_as_float(((unsigned)u) << 16); }
DEV unsigned short bfr_(float x){
  unsigned u = __float_as_uint(x);
  return (unsigned short)((u + 0x7FFFu + ((u >> 16) & 1u)) >> 16);
}
DEV short bf_split(float x, bool want_lo){
  unsigned u = __float_as_uint(x);
  unsigned hb = (u + 0x7FFFu + ((u >> 16) & 1u)) >> 16;
  if (!want_lo) return (short)hb;
  float lo = x - __uint_as_float(hb << 16);
  unsigned ul = __float_as_uint(lo);
  return (short)((ul + 0x7FFFu + ((ul >> 16) & 1u)) >> 16);
}

// ---------------- async global->LDS (16B) ----------------
DEV void gl16(const short* g, short* l){
  __builtin_amdgcn_global_load_lds((const __attribute__((address_space(1))) unsigned int*)g,
                                   (__attribute__((address_space(3))) unsigned int*)l, 16, 0, 0);
}
DEV void stage64(const short* g, short* lds, int wv, int lane, int ldk){
  #pragma unroll
  for (int j = 0; j < 4; ++j){
    const int r0 = (wv << 5) + (j << 3);
    const int row = r0 + (lane >> 3);
    const int c = (lane & 7) ^ (row & 7);
    gl16(g + (size_t)row*ldk + (c << 3), lds + (r0 << 6));
  }
}
DEV int swz(int row, int cc){ return (row << 6) + (((cc) ^ (row & 7)) << 3); }

// ---------------- fp32 GEMM (m2's K<=64 streaming shapes) ----------------
template<int ACT, int RES>
__global__ __launch_bounds__(256)
void gemm_k(const float* __restrict__ A, int lda,
            const float* __restrict__ W,
            const float* __restrict__ bias,
            const float* __restrict__ Rres,
            float* __restrict__ C, int ldc,
            int M, int N, int K)
{
  __shared__ float As[16][68];
  __shared__ float Ws[16][68];
  const int bm = blockIdx.x << 6;
  const int bn = blockIdx.y << 6;
  const int tid = threadIdx.x;
  const int tm0 = (tid >> 4) << 2;
  const int tn0 = (tid & 15) << 2;
  const int r   = tid >> 2;
  const int kk4 = (tid & 3) << 2;
  float acc[4][4] = {};
  for (int k0 = 0; k0 < K; k0 += 16) {
    const int gk = k0 + kk4;
    float4 va = make_float4(0.f,0.f,0.f,0.f);
    const int gr = bm + r;
    if (gr < M && gk < K) va = *(const float4*)(A + (size_t)gr*lda + gk);
    As[kk4+0][r]=va.x; As[kk4+1][r]=va.y; As[kk4+2][r]=va.z; As[kk4+3][r]=va.w;
    float4 vw = make_float4(0.f,0.f,0.f,0.f);
    const int gc = bn + r;
    if (gc < N && gk < K) vw = *(const float4*)(W + (size_t)gc*K + gk);
    Ws[kk4+0][r]=vw.x; Ws[kk4+1][r]=vw.y; Ws[kk4+2][r]=vw.z; Ws[kk4+3][r]=vw.w;
    __syncthreads();
    #pragma unroll
    for (int kk = 0; kk < 16; ++kk) {
      const float a0=As[kk][tm0+0], a1=As[kk][tm0+1], a2=As[kk][tm0+2], a3=As[kk][tm0+3];
      const float w0=Ws[kk][tn0+0], w1=Ws[kk][tn0+1], w2=Ws[kk][tn0+2], w3=Ws[kk][tn0+3];
      acc[0][0]+=a0*w0; acc[0][1]+=a0*w1; acc[0][2]+=a0*w2; acc[0][3]+=a0*w3;
      acc[1][0]+=a1*w0; acc[1][1]+=a1*w1; acc[1][2]+=a1*w2; acc[1][3]+=a1*w3;
      acc[2][0]+=a2*w0; acc[2][1]+=a2*w1; acc[2][2]+=a2*w2; acc[2][3]+=a2*w3;
      acc[3][0]+=a3*w0; acc[3][1]+=a3*w1; acc[3][2]+=a3*w2; acc[3][3]+=a3*w3;
    }
    __syncthreads();
  }
  #pragma unroll
  for (int i=0;i<4;i++){
    const int row = bm + tm0 + i;
    if (row >= M) continue;
    #pragma unroll
    for (int j=0;j<4;j++){
      const int col = bn + tn0 + j;
      if (col >= N) continue;
      float v = acc[i][j];
      if (bias) v += bias[col];
      if (RES)  v += Rres[(size_t)row*ldc + col];
      if (ACT == 1) v = softplus_(v);
      C[(size_t)row*ldc + col] = v;
    }
  }
}

// ---------------- vectorized split conversion ----------------
// MODE 0: [hi|lo|hi] (W triple), 1: [hi|hi|lo] (A triple), 2: [hi|lo] (duo)
template<int C, int KP, int MODE>
__global__ void cvt3t_k(const float* __restrict__ X, int ldx, short* __restrict__ Y,
                        int realR, int total4)
{
  const int i4 = blockIdx.x*256 + threadIdx.x;
  if (i4 >= total4) return;
  const int idx = i4 << 2;
  const int c3 = idx % KP;
  const int r  = idx / KP;
  short4v out = {0,0,0,0};
  const int nparts = (MODE == 2) ? 2 : 3;
  if (r < realR && c3 < nparts*C) {
    const int part = c3 / C;
    const int c = c3 - part*C;
    const bool lo = (MODE == 1) ? (part == 2) : (part == 1);
    const float4 v = *(const float4*)(X + (size_t)r*ldx + c);
    out.x = bf_split(v.x, lo); out.y = bf_split(v.y, lo);
    out.z = bf_split(v.z, lo); out.w = bf_split(v.w, lo);
  }
  *(short4v*)(Y + (size_t)r*KP + c3) = out;
}

// ---------------- glds MFMA GEMM 128x128, BK=64, direct output (triple layout) ----------------
template<int ACT, int RES, int BIAS>
__global__ __launch_bounds__(256)
void gemm3g_k(const short* __restrict__ A3, const short* __restrict__ W3,
              const float* __restrict__ bias, const float* __restrict__ Rres,
              float* __restrict__ C, int ldc, int NOUT, int M, int K3)
{
  __shared__ __align__(16) short As[128*64];
  __shared__ __align__(16) short Ws[128*64];
  const int tid = threadIdx.x;
  const int lane = tid & 63;
  const int wv = tid >> 6;
  const int bm = blockIdx.x << 7;
  const int bn = blockIdx.y << 7;
  const int wr = (wv >> 1) << 6;
  const int wc = (wv & 1) << 6;
  const int frow = lane & 15;
  const int fk = lane >> 4;
  floatx4 acc[4][4] = {};
  const short* gA = A3 + (size_t)bm*K3;
  const short* gW = W3 + (size_t)bn*K3;
  for (int k0 = 0; k0 < K3; k0 += 64) {
    __syncthreads();
    stage64(gA + k0, As, wv, lane, K3);
    stage64(gW + k0, Ws, wv, lane, K3);
    __syncthreads();
    #pragma unroll
    for (int kk = 0; kk < 2; ++kk) {
      short8v af[4], bfv[4];
      #pragma unroll
      for (int mf = 0; mf < 4; ++mf)
        af[mf] = *(const short8v*)&As[swz(wr + mf*16 + frow, kk*4 + fk)];
      #pragma unroll
      for (int nf = 0; nf < 4; ++nf)
        bfv[nf] = *(const short8v*)&Ws[swz(wc + nf*16 + frow, kk*4 + fk)];
      #pragma unroll
      for (int mf = 0; mf < 4; ++mf)
        #pragma unroll
        for (int nf = 0; nf < 4; ++nf)
          acc[mf][nf] = __builtin_amdgcn_mfma_f32_16x16x32_bf16(af[mf], bfv[nf], acc[mf][nf], 0, 0, 0);
    }
  }
  #pragma unroll
  for (int mf = 0; mf < 4; ++mf) {
    #pragma unroll
    for (int nf = 0; nf < 4; ++nf) {
      const int col = bn + wc + nf*16 + (lane & 15);
      if (col >= NOUT) continue;
      #pragma unroll
      for (int r = 0; r < 4; ++r) {
        const int row = bm + wr + mf*16 + (lane >> 4)*4 + r;
        float v = acc[mf][nf][r];
        if (BIAS) v += bias[col];
        if (RES)  v += Rres[(size_t)row*ldc + col];
        if (ACT == 1) v = softplus_(v);
        C[(size_t)row*ldc + col] = v;
      }
    }
  }
}

// ---------------- duo-layout 128x64 direct-output GEMM: Ah*Wh + Ah*Wl + Al*Wh ----------------
// 48 KB LDS -> 3 blocks/CU resident; grid (M/128, N/64) for occupancy on 256 CUs.
__global__ __launch_bounds__(256)
void gemm3gd64_k(const short* __restrict__ A2, const short* __restrict__ W2,
                 float* __restrict__ C, int ldc, int M, int K)
{
  __shared__ __align__(16) short Ash[128*64];
  __shared__ __align__(16) short Asl[128*64];
  __shared__ __align__(16) short Wsh[64*64];
  __shared__ __align__(16) short Wsl[64*64];
  const int tid = threadIdx.x;
  const int lane = tid & 63;
  const int wv = tid >> 6;
  const int bm = blockIdx.x << 7;
  const int bn = blockIdx.y << 6;
  const int wr = (wv >> 1) << 6;
  const int wc = (wv & 1) << 5;
  const int frow = lane & 15;
  const int fk = lane >> 4;
  floatx4 acc[4][2] = {};
  const short* gA = A2 + (size_t)bm*(2*K);
  const short* gW = W2 + (size_t)bn*(2*K);
  for (int k0 = 0; k0 < K; k0 += 64) {
    __syncthreads();
    stage64(gA + k0,     Ash, wv, lane, 2*K);
    stage64(gA + k0 + K, Asl, wv, lane, 2*K);
    {
      // stage W 64x64: each wave stages 16 rows (2 x 8-row passes)
      const int r0 = wv << 4;
      #pragma unroll
      for (int j = 0; j < 2; ++j) {
        const int rr = r0 + (j << 3);
        const int row = rr + (lane >> 3);
        const int c = (lane & 7) ^ (row & 7);
        gl16(gW + k0 +     (size_t)row*(2*K) + (c << 3), Wsh + (rr << 6));
        gl16(gW + k0 + K + (size_t)row*(2*K) + (c << 3), Wsl + (rr << 6));
      }
    }
    __syncthreads();
    #pragma unroll
    for (int kk = 0; kk < 2; ++kk) {
      short8v ah[4], bh[2];
      #pragma unroll
      for (int mf = 0; mf < 4; ++mf)
        ah[mf] = *(const short8v*)&Ash[swz(wr + mf*16 + frow, kk*4 + fk)];
      #pragma unroll
      for (int nf = 0; nf < 2; ++nf)
        bh[nf] = *(const short8v*)&Wsh[swz(wc + nf*16 + frow, kk*4 + fk)];
      #pragma unroll
      for (int mf = 0; mf < 4; ++mf)
        #pragma unroll
        for (int nf = 0; nf < 2; ++nf)
          acc[mf][nf] = __builtin_amdgcn_mfma_f32_16x16x32_bf16(ah[mf], bh[nf], acc[mf][nf], 0, 0, 0);
      // Ah * Wl
      #pragma unroll
      for (int nf = 0; nf < 2; ++nf) {
        const short8v bl = *(const short8v*)&Wsl[swz(wc + nf*16 + frow, kk*4 + fk)];
        #pragma unroll
        for (int mf = 0; mf < 4; ++mf)
          acc[mf][nf] = __builtin_amdgcn_mfma_f32_16x16x32_bf16(ah[mf], bl, acc[mf][nf], 0, 0, 0);
      }
      // Al * Wh
      #pragma unroll
      for (int mf = 0; mf < 4; ++mf) {
        const short8v al = *(const short8v*)&Asl[swz(wr + mf*16 + frow, kk*4 + fk)];
        #pragma unroll
        for (int nf = 0; nf < 2; ++nf)
          acc[mf][nf] = __builtin_amdgcn_mfma_f32_16x16x32_bf16(al, bh[nf], acc[mf][nf], 0, 0, 0);
      }
    }
  }
  #pragma unroll
  for (int mf = 0; mf < 4; ++mf) {
    #pragma unroll
    for (int nf = 0; nf < 2; ++nf) {
      const int col = bn + wc + nf*16 + (lane & 15);
      #pragma unroll
      for (int r = 0; r < 4; ++r) {
        const int row = bm + wr + mf*16 + (lane >> 4)*4 + r;
        C[(size_t)row*ldc + col] = acc[mf][nf][r];
      }
    }
  }
}

// ---------------- duo-layout 128x128 split-K 3-product GEMM: z = K-chunk planes, NOUT mask ----------------
__global__ __launch_bounds__(256)
void gemm3gdz_k(const short* __restrict__ A2, const short* __restrict__ W2,
                float* __restrict__ C, int ldc, int NOUT, int M, int K, int KC)
{
  __shared__ __align__(16) short Ash[128*64];
  __shared__ __align__(16) short Asl[128*64];
  __shared__ __align__(16) short Wsh[128*64];
  __shared__ __align__(16) short Wsl[128*64];
  const int tid = threadIdx.x;
  const int lane = tid & 63;
  const int wv = tid >> 6;
  const int bm = blockIdx.x << 7;
  const int bn = blockIdx.y << 7;
  const int kbeg = blockIdx.z * KC;
  float* Cpart = C + (size_t)blockIdx.z * M * ldc;
  const int wr = (wv >> 1) << 6;
  const int wc = (wv & 1) << 6;
  const int frow = lane & 15;
  const int fk = lane >> 4;
  floatx4 acc[4][4] = {};
  const short* gA = A2 + (size_t)bm*(2*K) + kbeg;
  const short* gW = W2 + (size_t)bn*(2*K) + kbeg;
  for (int k0 = 0; k0 < KC; k0 += 64) {
    __syncthreads();
    stage64(gA + k0,     Ash, wv, lane, 2*K);
    stage64(gA + k0 + K, Asl, wv, lane, 2*K);
    stage64(gW + k0,     Wsh, wv, lane, 2*K);
    stage64(gW + k0 + K, Wsl, wv, lane, 2*K);
    __syncthreads();
    #pragma unroll
    for (int kk = 0; kk < 2; ++kk) {
      short8v ah[4], bh[4];
      #pragma unroll
      for (int mf = 0; mf < 4; ++mf)
        ah[mf] = *(const short8v*)&Ash[swz(wr + mf*16 + frow, kk*4 + fk)];
      #pragma unroll
      for (int nf = 0; nf < 4; ++nf)
        bh[nf] = *(const short8v*)&Wsh[swz(wc + nf*16 + frow, kk*4 + fk)];
      #pragma unroll
      for (int mf = 0; mf < 4; ++mf)
        #pragma unroll
        for (int nf = 0; nf < 4; ++nf)
          acc[mf][nf] = __builtin_amdgcn_mfma_f32_16x16x32_bf16(ah[mf], bh[nf], acc[mf][nf], 0, 0, 0);
      #pragma unroll
      for (int nf = 0; nf < 4; ++nf) {
        const short8v bl = *(const short8v*)&Wsl[swz(wc + nf*16 + frow, kk*4 + fk)];
        #pragma unroll
        for (int mf = 0; mf < 4; ++mf)
          acc[mf][nf] = __builtin_amdgcn_mfma_f32_16x16x32_bf16(ah[mf], bl, acc[mf][nf], 0, 0, 0);
      }
      #pragma unroll
      for (int mf = 0; mf < 4; ++mf) {
        const short8v al = *(const short8v*)&Asl[swz(wr + mf*16 + frow, kk*4 + fk)];
        #pragma unroll
        for (int nf = 0; nf < 4; ++nf)
          acc[mf][nf] = __builtin_amdgcn_mfma_f32_16x16x32_bf16(al, bh[nf], acc[mf][nf], 0, 0, 0);
      }
    }
  }
  #pragma unroll
  for (int mf = 0; mf < 4; ++mf) {
    #pragma unroll
    for (int nf = 0; nf < 4; ++nf) {
      const int col = bn + wc + nf*16 + (lane & 15);
      if (col >= NOUT) continue;
      #pragma unroll
      for (int r = 0; r < 4; ++r) {
        const int row = bm + wr + mf*16 + (lane >> 4)*4 + r;
        Cpart[(size_t)row*ldc + col] = acc[mf][nf][r];
      }
    }
  }
}

// ---------------- glds split-K partial-plane GEMM (triple layout, feat only) ----------------
__global__ __launch_bounds__(256)
void gemm3gz_k(const short* __restrict__ A3, const short* __restrict__ W3,
               float* __restrict__ C, int ldc, int NOUT, int M, int K3, int KC)
{
  __shared__ __align__(16) short As[128*64];
  __shared__ __align__(16) short Ws[128*64];
  const int tid = threadIdx.x;
  const int lane = tid & 63;
  const int wv = tid >> 6;
  const int bm = blockIdx.x << 7;
  const int bn = blockIdx.y << 7;
  const int kbeg = blockIdx.z * KC;
  float* Cpart = C + (size_t)blockIdx.z * M * ldc;
  const int wr = (wv >> 1) << 6;
  const int wc = (wv & 1) << 6;
  const int frow = lane & 15;
  const int fk = lane >> 4;
  floatx4 acc[4][4] = {};
  const short* gA = A3 + (size_t)bm*K3 + kbeg;
  const short* gW = W3 + (size_t)bn*K3 + kbeg;
  for (int k0 = 0; k0 < KC; k0 += 64) {
    __syncthreads();
    stage64(gA + k0, As, wv, lane, K3);
    stage64(gW + k0, Ws, wv, lane, K3);
    __syncthreads();
    #pragma unroll
    for (int kk = 0; kk < 2; ++kk) {
      short8v af[4], bfv[4];
      #pragma unroll
      for (int mf = 0; mf < 4; ++mf)
        af[mf] = *(const short8v*)&As[swz(wr + mf*16 + frow, kk*4 + fk)];
      #pragma unroll
      for (int nf = 0; nf < 4; ++nf)
        bfv[nf] = *(const short8v*)&Ws[swz(wc + nf*16 + frow, kk*4 + fk)];
      #pragma unroll
      for (int mf = 0; mf < 4; ++mf)
        #pragma unroll
        for (int nf = 0; nf < 4; ++nf)
          acc[mf][nf] = __builtin_amdgcn_mfma_f32_16x16x32_bf16(af[mf], bfv[nf], acc[mf][nf], 0, 0, 0);
    }
  }
  #pragma unroll
  for (int mf = 0; mf < 4; ++mf) {
    #pragma unroll
    for (int nf = 0; nf < 4; ++nf) {
      const int col = bn + wc + nf*16 + (lane & 15);
      if (col >= NOUT) continue;
      #pragma unroll
      for (int r = 0; r < 4; ++r) {
        const int row = bm + wr + mf*16 + (lane >> 4)*4 + r;
        Cpart[(size_t)row*ldc + col] = acc[mf][nf][r];
      }
    }
  }
}

// ---------------- duo-layout N=32 split-K patch GEMM ----------------
__global__ __launch_bounds__(256)
void gemm3gd32_k(const short* __restrict__ A2, const short* __restrict__ W2,
                 float* __restrict__ C, int M, int K, int KC)
{
  __shared__ __align__(16) short Ash[128*64];
  __shared__ __align__(16) short Asl[128*64];
  __shared__ __align__(16) short Wsh[32*64];
  __shared__ __align__(16) short Wsl[32*64];
  const int tid = threadIdx.x;
  const int lane = tid & 63;
  const int wv = tid >> 6;
  const int bm = blockIdx.x << 7;
  const int kbeg = blockIdx.z * KC;
  float* Cpart = C + (size_t)blockIdx.z * M * 32;
  const int wr = wv << 5;
  const int frow = lane & 15;
  const int fk = lane >> 4;
  floatx4 acc[2][2] = {};
  const short* gA = A2 + (size_t)bm*(2*K) + kbeg;
  const short* gW = W2 + kbeg;
  for (int k0 = 0; k0 < KC; k0 += 64) {
    __syncthreads();
    stage64(gA + k0,     Ash, wv, lane, 2*K);
    stage64(gA + k0 + K, Asl, wv, lane, 2*K);
    {
      const int r0 = wv << 3;
      const int row = r0 + (lane >> 3);
      const int c = (lane & 7) ^ (row & 7);
      gl16(gW + k0 +     (size_t)row*(2*K) + (c << 3), Wsh + (r0 << 6));
      gl16(gW + k0 + K + (size_t)row*(2*K) + (c << 3), Wsl + (r0 << 6));
    }
    __syncthreads();
    #pragma unroll
    for (int kk = 0; kk < 2; ++kk) {
      short8v ah[2], al[2], bh[2], blv[2];
      #pragma unroll
      for (int mf = 0; mf < 2; ++mf) {
        ah[mf] = *(const short8v*)&Ash[swz(wr + mf*16 + frow, kk*4 + fk)];
        al[mf] = *(const short8v*)&Asl[swz(wr + mf*16 + frow, kk*4 + fk)];
      }
      #pragma unroll
      for (int nf = 0; nf < 2; ++nf) {
        bh[nf]  = *(const short8v*)&Wsh[swz(nf*16 + frow, kk*4 + fk)];
        blv[nf] = *(const short8v*)&Wsl[swz(nf*16 + frow, kk*4 + fk)];
      }
      #pragma unroll
      for (int mf = 0; mf < 2; ++mf)
        #pragma unroll
        for (int nf = 0; nf < 2; ++nf) {
          acc[mf][nf] = __builtin_amdgcn_mfma_f32_16x16x32_bf16(ah[mf], bh[nf],  acc[mf][nf], 0, 0, 0);
          acc[mf][nf] = __builtin_amdgcn_mfma_f32_16x16x32_bf16(ah[mf], blv[nf], acc[mf][nf], 0, 0, 0);
          acc[mf][nf] = __builtin_amdgcn_mfma_f32_16x16x32_bf16(al[mf], bh[nf],  acc[mf][nf], 0, 0, 0);
        }
    }
  }
  #pragma unroll
  for (int mf = 0; mf < 2; ++mf) {
    #pragma unroll
    for (int nf = 0; nf < 2; ++nf) {
      const int col = nf*16 + (lane & 15);
      #pragma unroll
      for (int r = 0; r < 4; ++r) {
        const int row = bm + wr + mf*16 + (lane >> 4)*4 + r;
        Cpart[(size_t)row*32 + col] = acc[mf][nf][r];
      }
    }
  }
}

// ---------------- split-K reduce kernels ----------------
__global__ void reduce_xp_k(const float* __restrict__ part, float* __restrict__ out)
{
  const int i = blockIdx.x*256 + threadIdx.x;   // 2048*80
  if (i >= 163840) return;
  float s = 0.f;
  #pragma unroll
  for (int z = 0; z < 8; ++z) s += part[(size_t)z*163840 + i];
  out[i] = s;
}
__global__ void reduce_feat_k(const float* __restrict__ part, const float* __restrict__ bias,
                              float* __restrict__ out)
{
  const int i = blockIdx.x*256 + threadIdx.x;   // 1024*128
  if (i >= 131072) return;
  const int r = i >> 7, c = i & 127;
  float s = bias[c];
  #pragma unroll
  for (int z = 0; z < 8; ++z) s += part[(size_t)z*131072 + i];
  out[(size_t)r*256 + 128 + c] = s;
}
// reduce out-proj 3 planes + residual; optionally emit next layer's A2i duo
template<int EMIT>
__global__ void reduce_out3_k(const float* __restrict__ p0, float* __restrict__ m1x,
                              short* __restrict__ A2i)
{
  const int i = blockIdx.x*256 + threadIdx.x;   // 2048*768
  if (i >= 1572864) return;
  float s = m1x[i];
  #pragma unroll
  for (int z = 0; z < 3; ++z) s += p0[(size_t)z*1572864 + i];
  m1x[i] = s;
  if (EMIT) {
    const int d = i % 768;
    const int sl = i / 768;
    const short hi = bf_split(s,false), lo = bf_split(s,true);
    short* p = A2i + (size_t)sl*1536 + d;
    p[0] = hi; p[768] = lo;
  }
}

// ---------------- m1 delta projection: streaming K=48 ----------------
__global__ __launch_bounds__(256)
void dt1_k(const float* __restrict__ dbl, const float* __restrict__ dt_w,
           const float* __restrict__ dt_b, float* __restrict__ delta)
{
  const int d = blockIdx.y*256 + threadIdx.x;
  const int r0 = blockIdx.x*8;
  float w[48];
  #pragma unroll
  for (int q = 0; q < 12; ++q)
    *(float4*)&w[q*4] = *(const float4*)(dt_w + (size_t)d*48 + q*4);
  __shared__ float sdbl[8][48];
  if (threadIdx.x < 96) {
    const int rr = threadIdx.x / 12, q = threadIdx.x % 12;
    *(float4*)&sdbl[rr][q*4] = *(const float4*)(dbl + (size_t)(r0+rr)*80 + q*4);
  }
  __syncthreads();
  const float bv = dt_b[d];
  #pragma unroll
  for (int rr = 0; rr < 8; ++rr) {
    float acc = bv;
    #pragma unroll
    for (int k = 0; k < 48; ++k) acc += sdbl[rr][k]*w[k];
    delta[(size_t)(r0+rr)*1536 + d] = softplus_(acc);
  }
}

// ---------------- patch conv im2col -> duo-split bf16 [hi|lo] ----------------
__global__ void im2col2_k(const float* __restrict__ x, int c0, short* __restrict__ A2)
{
  const int t = blockIdx.x*256 + threadIdx.x;
  if (t >= 2097152) return;
  const int b = t >> 16;
  const int r = t & 65535;
  const int c = r >> 12;
  const int f = r & 4095;
  const float4 v = *(const float4*)(x + (((size_t)b*32 + c0 + c) << 14) + (f << 2));
  const int o4 = f << 2;
  const int h = o4 >> 7, w = o4 & 127;
  const int patch = ((h >> 4) << 3) + (w >> 4);
  const int pos = ((h & 15) << 4) + (w & 15);
  const int row = (b << 6) + patch;
  const int k = (c << 8) + pos;
  short4v hv, lv;
  hv.x = bf_split(v.x,false); lv.x = bf_split(v.x,true);
  hv.y = bf_split(v.y,false); lv.y = bf_split(v.y,true);
  hv.z = bf_split(v.z,false); lv.z = bf_split(v.z,true);
  hv.w = bf_split(v.w,false); lv.w = bf_split(v.w,true);
  short* base = A2 + (size_t)row*8192 + k;
  *(short4v*)(base)        = hv;
  *(short4v*)(base + 4096) = lv;
}

__global__ void reduce_patch16_k(const float* __restrict__ part, const float* __restrict__ bias,
                                 short* __restrict__ A3p)
{
  const int idx = blockIdx.x*256 + threadIdx.x;
  if (idx >= 65536) return;
  const int patch = idx & 63;
  const int o = (idx >> 6) & 31;
  const int b = idx >> 11;
  const int row = (b << 6) + patch;
  float s = bias[o];
  #pragma unroll
  for (int z = 0; z < 32; ++z) s += part[(size_t)z*65536 + row*32 + o];
  const short hi = bf_split(s,false), lo = bf_split(s,true);
  short* p = A3p + (size_t)((b << 5) + o)*192 + patch;
  p[0] = hi; p[64] = hi; p[128] = lo;
}

// ---------------- fused: x_proj assemble + gelu fuse + concat + layernorm ----------------
__global__ __launch_bounds__(256)
void fuse_ln_k(const float* __restrict__ xpat, const float* __restrict__ xprojbuf,
               const float* __restrict__ xfeat, const float* __restrict__ lnw,
               const float* __restrict__ lnb, const float* __restrict__ focusp,
               float* __restrict__ cat)
{
  const int row = blockIdx.x;
  const int t = threadIdx.x;
  const float focus = focusp[0];
  const float xp = xpat[(size_t)row*256 + t];
  const float pr = (t < 128) ? xfeat[(size_t)row*1280 + t] : xprojbuf[(size_t)row*256 + t];
  const float xf = gelu_(focus*pr + (2.f - focus)*xp);
  float s  = xp + xf + pr;
  float sq = xp*xp + xf*xf + pr*pr;
  __shared__ float rs[4], rq[4];
  const int lane = t & 63, wv = t >> 6;
  #pragma unroll
  for (int off = 32; off > 0; off >>= 1) {
    s  += __shfl_down(s,  off, 64);
    sq += __shfl_down(sq, off, 64);
  }
  if (lane == 0) { rs[wv] = s; rq[wv] = sq; }
  __syncthreads();
  const float S = rs[0]+rs[1]+rs[2]+rs[3];
  const float Q = rq[0]+rq[1]+rq[2]+rq[3];
  const float mu = S * (1.f/768.f);
  const float var = Q*(1.f/768.f) - mu*mu;
  const float rstd = rsqrtf(var + 1e-5f);
  const size_t ob = (size_t)row*768;
  cat[ob +        t] = (xp - mu)*rstd*lnw[      t] + lnb[      t];
  cat[ob + 256 +  t] = (xf - mu)*rstd*lnw[256 + t] + lnb[256 + t];
  cat[ob + 512 +  t] = (pr - mu)*rstd*lnw[512 + t] + lnb[512 + t];
}

// ---------------- prep: duplicate + flip (m1 also emits A2i duo) ----------------
__global__ void prep_m1_k(const float* __restrict__ cat, float* __restrict__ X,
                          short* __restrict__ A2i)
{
  const int idx = blockIdx.x*256 + threadIdx.x;
  if (idx >= 64*32*768) return;
  const int d = idx % 768;
  const int sl = idx / 768;
  const int l = sl & 31;
  const int s = sl >> 5;
  const int b = s & 31;
  const int ll = (s < 32) ? l : 31 - l;
  const float v = cat[((size_t)b*32 + ll)*768 + d];
  X[idx] = v;
  const short hi = bf_split(v,false), lo = bf_split(v,true);
  short* p = A2i + (size_t)sl*1536 + d;
  p[0] = hi; p[768] = lo;
}
__global__ void prep_m2_k(const float* __restrict__ cat, float* __restrict__ X)
{
  const int idx = blockIdx.x*256 + threadIdx.x;
  if (idx >= 64*768*32) return;
  const int c = idx & 31;
  const int sj = idx >> 5;
  const int j = sj % 768;
  const int s = sj / 768;
  const int b = (s < 32) ? s : s - 32;
  const int jj = (s < 32) ? j : 767 - j;
  X[idx] = cat[((size_t)b*32 + c)*768 + jj];
}

// ---------------- m2 depthwise causal conv (k=4) + silu ----------------
__global__ void dwconv_silu_k(const float* __restrict__ xz, int ldxz,
                              const float* __restrict__ w, const float* __restrict__ b,
                              float* __restrict__ xc, int di, int L, int total)
{
  const int idx = blockIdx.x*256 + threadIdx.x;
  if (idx >= total) return;
  const int d = idx % di;
  const int sl = idx / di;
  const int l = sl % L;
  float acc = b[d];
  const float* wd = w + d*4;
  #pragma unroll
  for (int k = 0; k < 4; ++k) {
    const int ll = l - 3 + k;
    if (ll >= 0) acc += xz[(size_t)(sl - 3 + k)*ldxz + d] * wd[k];
  }
  xc[idx] = silu_(acc);
}

// ---------------- m1 dwconv + silu, fused with duo A2x emit ----------------
__global__ void dwconv2_m1_k(const float* __restrict__ xz,
                             const float* __restrict__ w, const float* __restrict__ b,
                             float* __restrict__ xc, short* __restrict__ A2x)
{
  const int idx = blockIdx.x*256 + threadIdx.x;
  if (idx >= 3145728) return;
  const int d = idx % 1536;
  const int sl = idx / 1536;
  const int l = sl & 31;
  float acc = b[d];
  const float* wd = w + d*4;
  #pragma unroll
  for (int k = 0; k < 4; ++k) {
    const int ll = l - 3 + k;
    if (ll >= 0) acc += xz[(size_t)(sl - 3 + k)*3072 + d] * wd[k];
  }
  const float v = silu_(acc);
  xc[idx] = v;
  const short hi = bf_split(v,false), lo = bf_split(v,true);
  short* p = A2x + (size_t)sl*3072 + d;
  p[0] = hi; p[1536] = lo;
}

// ---------------- m2 dt projection (K=2) + softplus ----------------
__global__ void dt2_k(const float* __restrict__ dbl, const float* __restrict__ dt_w,
                      const float* __restrict__ dt_b, float* __restrict__ delta)
{
  const int idx = blockIdx.x*256 + threadIdx.x;
  if (idx >= 49152*64) return;
  const int d = idx & 63;
  const int r = idx >> 6;
  const float a0 = dbl[(size_t)r*34 + 0], a1 = dbl[(size_t)r*34 + 1];
  delta[idx] = softplus_(a0*dt_w[d*2] + a1*dt_w[d*2+1] + dt_b[d]);
}

// ---------------- m1 selective scan (L=32), 4-way state-split, fused A3o emit ----------------
__global__ __launch_bounds__(256)
void scan3s_m1_k(const float* __restrict__ delta, const float* __restrict__ xc,
                 const float* __restrict__ dbl, const float* __restrict__ z,
                 const float* __restrict__ A_log, const float* __restrict__ Dp,
                 short* __restrict__ A3o)
{
  const int s = blockIdx.x / 24;
  const int dchunk = blockIdx.x % 24;
  const int lane = threadIdx.x & 63;
  const int wv = threadIdx.x >> 6;
  const int d = dchunk*64 + wv*16 + (lane & 15);
  const int hf = lane >> 4;
  const int n0 = hf*4;
  float A[4], h[4];
  #pragma unroll
  for (int n = 0; n < 4; ++n) { A[n] = -__expf(A_log[d*16 + n0 + n]); h[n] = 0.f; }
  const float Dv = Dp[d];
  for (int l = 0; l < 32; ++l) {
    const size_t row = (size_t)s*32 + l;
    const float de  = delta[row*1536 + d];
    const float xcv = xc[row*1536 + d];
    const float du  = de * xcv;
    const float* bl = dbl + row*80 + 48 + n0;
    float y = 0.f;
    #pragma unroll
    for (int n = 0; n < 4; ++n) {
      const float dA = __expf(de * A[n]);
      h[n] = dA*h[n] + du*bl[n];
      y += h[n]*bl[16 + n];
    }
    y += __shfl_xor(y, 16);
    y += __shfl_xor(y, 32);
    if (hf == 0) {
      const float zv = z[row*3072 + d];
      const float out = (y + xcv*Dv) * silu_(zv);
      short* p = A3o + row*3072 + d;
      p[0] = bf_split(out,false);
      p[1536] = bf_split(out,true);
    }
  }
}

// ---------------- m2 chunked scan: 24 chunks of 32, 4-way state-split, bf16 Hend ----------------
#define NC2 24
#define LC2 32

__global__ __launch_bounds__(256)
void scan2_partA(const float* __restrict__ delta, const float* __restrict__ xc,
                 const float* __restrict__ dbl, const float* __restrict__ A_log,
                 unsigned short* __restrict__ Hend, unsigned short* __restrict__ sde_buf)
{
  const int s = blockIdx.x / NC2;
  const int c = blockIdx.x % NC2;
  const int lane = threadIdx.x & 63;
  const int wv = threadIdx.x >> 6;
  const int d = wv*16 + (lane & 15);
  const int hf = lane >> 4;
  const int n0 = hf*4;
  float A[4], h[4];
  #pragma unroll
  for (int n = 0; n < 4; ++n) { A[n] = -__expf(A_log[d*16 + n0 + n]); h[n] = 0.f; }
  float sde = 0.f;
  const size_t row0 = (size_t)s*768 + c*LC2;
  for (int l = 0; l < LC2; ++l) {
    const size_t row = row0 + l;
    const float de  = delta[row*64 + d];
    const float xcv = xc[row*64 + d];
    const float du  = de * xcv;
    const float* bl = dbl + row*34 + 2 + n0;
    sde += de;
    #pragma unroll
    for (int n = 0; n < 4; ++n)
      h[n] = __expf(de*A[n])*h[n] + du*bl[n];
  }
  short4v hv;
  hv.x = (short)bfr_(h[0]); hv.y = (short)bfr_(h[1]);
  hv.z = (short)bfr_(h[2]); hv.w = (short)bfr_(h[3]);
  *(short4v*)(Hend + ((size_t)((s*NC2 + c)*64 + d))*16 + n0) = hv;
  if (hf == 0) sde_buf[(s*NC2 + c)*64 + d] = bfr_(sde);
}

__global__ void scan2_carry(const float* __restrict__ A_log,
                            unsigned short* __restrict__ Hend,
                            const unsigned short* __restrict__ sde_buf)
{
  const int t = blockIdx.x*256 + threadIdx.x;
  if (t >= 4096) return;
  const int d = t & 63;
  const int s = t >> 6;
  float A[16], H[16];
  #pragma unroll
  for (int n = 0; n < 16; ++n) { A[n] = -__expf(A_log[d*16 + n]); H[n] = 0.f; }
  for (int c = 0; c < NC2; ++c) {
    const size_t off = ((size_t)(s*NC2 + c)*64 + d)*16;
    const float sde = bfu_(sde_buf[(s*NC2 + c)*64 + d]);
    #pragma unroll
    for (int n = 0; n < 16; ++n) {
      const float he = bfu_(Hend[off + n]);
      Hend[off + n] = bfr_(H[n]);
      H[n] = __expf(sde*A[n])*H[n] + he;
    }
  }
}

__global__ __launch_bounds__(256)
void scan2_partC(const float* __restrict__ delta, const float* __restrict__ xc,
                 const float* __restrict__ dbl, const float* __restrict__ z,
                 const float* __restrict__ A_log, const float* __restrict__ Dp,
                 const unsigned short* __restrict__ Hin, float* __restrict__ Y)
{
  const int s = blockIdx.x / NC2;
  const int c = blockIdx.x % NC2;
  const int lane = threadIdx.x & 63;
  const int wv = threadIdx.x >> 6;
  const int d = wv*16 + (lane & 15);
  const int hf = lane >> 4;
  const int n0 = hf*4;
  float A[4], h[4];
  const unsigned short* hp = Hin + ((size_t)((s*NC2 + c)*64 + d))*16 + n0;
  #pragma unroll
  for (int n = 0; n < 4; ++n) {
    A[n] = -__expf(A_log[d*16 + n0 + n]);
    h[n] = bfu_(hp[n]);
  }
  const float Dv = Dp[d];
  const size_t row0 = (size_t)s*768 + c*LC2;
  for (int l = 0; l < LC2; ++l) {
    const size_t row = row0 + l;
    const float de  = delta[row*64 + d];
    const float xcv = xc[row*64 + d];
    const float du  = de * xcv;
    const float* bl = dbl + row*34 + 2 + n0;
    float y = 0.f;
    #pragma unroll
    for (int n = 0; n < 4; ++n) {
      const float dA = __expf(de*A[n]);
      h[n] = dA*h[n] + du*bl[n];
      y += h[n]*bl[16 + n];
    }
    y += __shfl_xor(y, 16);
    y += __shfl_xor(y, 32);
    if (hf == 0) {
      const float zv = z[row*128 + d];
      Y[row*64 + d] = (y + xcv*Dv) * silu_(zv);
    }
  }
}

// ---------------- x3 combine + mean (parallel) ----------------
__global__ __launch_bounds__(256)
void x3_k(const float* __restrict__ x1p, const float* __restrict__ x2p, float* __restrict__ x3)
{
  const int b = blockIdx.x / 24;
  const int jc = blockIdx.x % 24;
  const int jl = threadIdx.x & 31;
  const int ig = threadIdx.x >> 5;
  const int j = jc*32 + jl;
  float s = 0.f;
  #pragma unroll
  for (int q = 0; q < 4; ++q) {
    const int i = ig*4 + q;
    s += x1p[((size_t)b*32 + i)*768 + j] + x1p[((size_t)(b+32)*32 + i)*768 + j];
    s += x2p[((size_t)b*768 + j)*32 + i] + x2p[((size_t)(b+32)*768 + j)*32 + i];
  }
  __shared__ float red[8][33];
  red[ig][jl] = s;
  __syncthreads();
  if (ig == 0) {
    float t = 0.f;
    #pragma unroll
    for (int g = 0; g < 8; ++g) t += red[g][jl];
    x3[(size_t)b*768 + j] = t * (1.f/32.f);
  }
}

// ---------------- head stage 1 ----------------
__global__ __launch_bounds__(256)
void head1_k(const float* __restrict__ x3, const float* __restrict__ w1,
             const float* __restrict__ b1, const float* __restrict__ w2,
             float* __restrict__ h)
{
  const int b = blockIdx.x;
  const int lane = threadIdx.x & 63;
  const int wv = threadIdx.x >> 6;
  const int t = blockIdx.y*4 + wv;
  float dot = 0.f;
  const float* xr = x3 + (size_t)b*768;
  const float* wr = w1 + (size_t)t*768;
  #pragma unroll
  for (int k = 0; k < 12; ++k)
    dot += xr[lane + k*64] * wr[lane + k*64];
  #pragma unroll
  for (int off = 32; off > 0; off >>= 1) dot += __shfl_down(dot, off, 64);
  if (lane == 0) h[(size_t)b*384 + t] = (dot + b1[t]) * w2[t];
}

// ---------------- head stage 2 ----------------
__global__ __launch_bounds__(64)
void head2_k(const float* __restrict__ h, const float* __restrict__ b2,
             float* __restrict__ out)
{
  const int b = blockIdx.x;
  const int lane = threadIdx.x;
  float s = 0.f;
  #pragma unroll
  for (int k = 0; k < 6; ++k) s += h[(size_t)b*384 + k*64 + lane];
  #pragma unroll
  for (int off = 32; off > 0; off >>= 1) s += __shfl_down(s, off, 64);
  if (lane == 0) out[b] = s + b2[0];
}

extern "C" void kernel_launch(void* const* d_in, const int* in_sizes, int n_in,
                              void* d_out, int out_size, void* d_ws, size_t ws_size,
                              hipStream_t stream)
{
  (void)in_sizes; (void)n_in; (void)out_size;
  const float* x_cwt        = (const float*)d_in[0];
  const float* x_features   = (const float*)d_in[1];
  const float* patch_conv_w = (const float*)d_in[2];
  const float* patch_conv_b = (const float*)d_in[3];
  const float* patch_proj_w = (const float*)d_in[4];
  const float* patch_proj_b = (const float*)d_in[5];
  const float* feat_proj_w  = (const float*)d_in[6];
  const float* feat_proj_b  = (const float*)d_in[7];
  const float* ln_w         = (const float*)d_in[8];
  const float* ln_b         = (const float*)d_in[9];
  const float* focus        = (const float*)d_in[10];
  const float* reg_w1       = (const float*)d_in[11];
  const float* reg_b1       = (const float*)d_in[12];
  const float* reg_w2       = (const float*)d_in[13];
  const float* reg_b2       = (const float*)d_in[14];
  const float* m1w[9]; for (int i=0;i<9;i++) m1w[i] = (const float*)d_in[15+i];
  const float* m2w[9]; for (int i=0;i<9;i++) m2w[i] = (const float*)d_in[24+i];

  // ---- arena (floats), 21,356,544 fl ----
  float* p = (float*)d_ws;
  size_t need = 0;
  auto alloc = [&](size_t n){ float* r = p; p += n; need += n; return r; };
  float* cat    = alloc(786432);    // front/m1: cat | m2 loop: Hend (bf16)
  float* m1x    = alloc(1572864);
  float* m2x    = alloc(1572864);
  float* x3     = alloc(24576);     // m2 loop: sde | end: x3
  float* bxz    = alloc(6291456);
  float* bxc    = alloc(3145728);
  float* bdbl   = alloc(1671168);
  float* bdelta = alloc(3145728);
  float* by     = alloc(3145728);
  if (ws_size < need * sizeof(float)) return;

  // ---- overlays (liveness traced per stage) ----
  short* A2pc  = (short*)bxz;            // 2048x8192 sh
  short* W2pc  = (short*)by;             // 32x8192 sh per half
  float* pcpart = by + 800000;           // 32 x 65536 fl
  float* x_patched = m1x;                // 262,144
  float* x_projb   = m1x + 262144;       // 262,144
  short* A3p = (short*)(m1x + 524288);   // 1024x192 sh
  short* W3p = (short*)(m1x + 630016);   // 256x192 sh
  short* A3f = (short*)bxz;              // 1024x3072 sh
  short* W3f = (short*)(bxz + 1600000);  // 128x3072 sh
  float* featpart = m2x;                 // 8 x 131072 fl
  short* A2i  = (short*)bxc;             // 2048x1536 sh duo (prep_m1 / reduce_out3)
  short* W2i  = (short*)bdbl;            // 3072x1536 sh duo (bdbl+bdelta head)
  short* A2x  = (short*)bdbl;            // 2048x3072 sh duo = 3.15M fl (bdbl+bdelta head)
  short* W2x  = (short*)by;              // 128x3072 sh duo (zero-padded rows 80..127)
  float* xppart = m2x;                   // 8 x 163840 fl
  short* A3o  = (short*)by;              // 2048x3072 sh ([hi|lo]) = by exactly
  short* W3o  = (short*)bxc;             // 768x3072 sh ([hi|lo]) — dead before A2i emit
  float* outp0 = bxz;                    // 3 planes x 1,572,864 fl (z dead after scan3)
  unsigned short* sHend = (unsigned short*)cat;
  unsigned short* sSde  = (unsigned short*)x3;
  float* hbuf = bxz;                     // 32x384 fl (bxz dead after m2 loop)

  // ---- patch conv: 2 halves of duo im2col + duo 3-product N32 split-K MFMA (z=16 each) ----
  im2col2_k<<<8192, 256, 0, stream>>>(x_cwt, 0, A2pc);
  cvt3t_k<4096,8192,2><<<256, 256, 0, stream>>>(patch_conv_w, 8192, W2pc, 32, 65536);
  gemm3gd32_k<<<dim3(16,1,16), 256, 0, stream>>>(A2pc, W2pc, pcpart, 2048, 4096, 256);
  im2col2_k<<<8192, 256, 0, stream>>>(x_cwt, 16, A2pc);
  cvt3t_k<4096,8192,2><<<256, 256, 0, stream>>>(patch_conv_w + 4096, 8192, W2pc, 32, 65536);
  gemm3gd32_k<<<dim3(16,1,16), 256, 0, stream>>>(A2pc, W2pc, pcpart + 16*65536, 2048, 4096, 256);
  reduce_patch16_k<<<256, 256, 0, stream>>>(pcpart, patch_conv_b, A3p);
  cvt3t_k<64,192,0><<<48, 256, 0, stream>>>(patch_proj_w, 64, W3p, 256, 12288);
  gemm3g_k<0,0,1><<<dim3(8,2), 256, 0, stream>>>(A3p, W3p, patch_proj_b, nullptr,
                                                 x_patched, 256, 256, 1024, 192);
  cvt3t_k<1024,3072,1><<<3072, 256, 0, stream>>>(x_features + 256, 1280, A3f, 1024, 786432);
  cvt3t_k<1024,3072,0><<<384, 256, 0, stream>>>(feat_proj_w, 1024, W3f, 128, 98304);
  gemm3gz_k<<<dim3(8,1,8), 256, 0, stream>>>(A3f, W3f, featpart, 128, 128, 1024, 3072, 384);
  reduce_feat_k<<<512, 256, 0, stream>>>(featpart, feat_proj_b, x_projb);
  fuse_ln_k<<<1024, 256, 0, stream>>>(x_patched, x_projb, x_features, ln_w, ln_b, focus, cat);
  prep_m1_k<<<6144, 256, 0, stream>>>(cat, m1x, A2i);

  // ---- m1: 2 layers on batched (64,32,768); di=1536, dr=48 ----
  for (int im = 0; im < 2; ++im) {
    const float* in_w   = m1w[0] + (size_t)im*3072*768;
    const float* conv_w = m1w[1] + (size_t)im*1536*4;
    const float* conv_b = m1w[2] + (size_t)im*1536;
    const float* xp_w   = m1w[3] + (size_t)im*80*1536;
    const float* dt_w   = m1w[4] + (size_t)im*1536*48;
    const float* dt_b   = m1w[5] + (size_t)im*1536;
    const float* A_log  = m1w[6] + (size_t)im*1536*16;
    const float* Dp     = m1w[7] + (size_t)im*1536;
    const float* out_w  = m1w[8] + (size_t)im*768*1536;
    // in-proj: duo 3-product direct GEMM (K=768), 128x64 tile for 768-block occupancy
    cvt3t_k<768,1536,2><<<4608, 256, 0, stream>>>(in_w, 768, W2i, 3072, 1179648);
    gemm3gd64_k<<<dim3(16,48), 256, 0, stream>>>(A2i, W2i, bxz, 3072, 2048, 768);
    // dwconv + silu, duo A2x emit
    dwconv2_m1_k<<<12288, 256, 0, stream>>>(bxz, conv_w, conv_b, bxc, A2x);
    // xp: duo 3-product split-K z=8 (KC=192) -> 8 planes -> reduce into bdbl
    cvt3t_k<1536,3072,2><<<384, 256, 0, stream>>>(xp_w, 1536, W2x, 80, 98304);
    gemm3gdz_k<<<dim3(16,1,8), 256, 0, stream>>>(A2x, W2x, xppart, 80, 80, 2048, 1536, 192);
    reduce_xp_k<<<640, 256, 0, stream>>>(xppart, bdbl);
    dt1_k<<<dim3(256,6), 256, 0, stream>>>(bdbl, dt_w, dt_b, bdelta);
    scan3s_m1_k<<<1536, 256, 0, stream>>>(bdelta, bxc, bdbl, bxz + 1536, A_log, Dp, A3o);
    // out-proj: duo 3-product split-K (z=3 K-chunks of 512) -> 3 planes -> reduce
    cvt3t_k<1536,3072,2><<<2304, 256, 0, stream>>>(out_w, 1536, W3o, 768, 589824);
    gemm3gdz_k<<<dim3(16,6,3), 256, 0, stream>>>(A3o, W3o, outp0, 768, 768, 2048, 1536, 512);
    if (im == 0) reduce_out3_k<1><<<6144, 256, 0, stream>>>(outp0, m1x, A2i);
    else         reduce_out3_k<0><<<6144, 256, 0, stream>>>(outp0, m1x, nullptr);
  }

  // ---- m2 prep (cat still alive; becomes Hend afterwards) ----
  prep_m2_k<<<6144, 256, 0, stream>>>(cat, m2x);

  // ---- m2: 2 layers on batched (64,768,32); di=64, dr=2 ----
  for (int im = 0; im < 2; ++im) {
    const float* in_w   = m2w[0] + (size_t)im*128*32;
    const float* conv_w = m2w[1] + (size_t)im*64*4;
    const float* conv_b = m2w[2] + (size_t)im*64;
    const float* xp_w   = m2w[3] + (size_t)im*34*64;
    const float* dt_w   = m2w[4] + (size_t)im*64*2;
    const float* dt_b   = m2w[5] + (size_t)im*64;
    const float* A_log  = m2w[6] + (size_t)im*64*16;
    const float* Dp     = m2w[7] + (size_t)im*64;
    const float* out_w  = m2w[8] + (size_t)im*32*64;
    gemm_k<0,0><<<dim3(768,2), 256, 0, stream>>>(m2x, 32, in_w, nullptr, nullptr,
                                                 bxz, 128, 49152, 128, 32);
    dwconv_silu_k<<<12288, 256, 0, stream>>>(bxz, 128, conv_w, conv_b, bxc, 64, 768, 49152*64);
    gemm_k<0,0><<<dim3(768,1), 256, 0, stream>>>(bxc, 64, xp_w, nullptr, nullptr,
                                                 bdbl, 34, 49152, 34, 64);
    dt2_k<<<12288, 256, 0, stream>>>(bdbl, dt_w, dt_b, bdelta);
    scan2_partA<<<1536, 256, 0, stream>>>(bdelta, bxc, bdbl, A_log, sHend, sSde);
    scan2_carry<<<16, 256, 0, stream>>>(A_log, sHend, sSde);
    scan2_partC<<<1536, 256, 0, stream>>>(bdelta, bxc, bdbl, bxz + 64, A_log, Dp, sHend, by);
    gemm_k<0,1><<<dim3(768,1), 256, 0, stream>>>(by, 64, out_w, nullptr, m2x,
                                                 m2x, 32, 49152, 32, 64);
  }

  // ---- head (parallel 3-stage) ----
  x3_k<<<768, 256, 0, stream>>>(m1x, m2x, x3);
  head1_k<<<dim3(32,96), 256, 0, stream>>>(x3, reg_w1, reg_b1, reg_w2, hbuf);
  head2_k<<<32, 64, 0, stream>>>(hbuf, reg_b2, (float*)d_out);
}